// Round 8
// baseline (383.278 us; speedup 1.0000x reference)
//
#include <hip/hip_runtime.h>
#include <hip/hip_cooperative_groups.h>
#include <math.h>

namespace cg = cooperative_groups;

// MemNN forward: B=64, S=200, T=32, E=128, V=50000, HOPS=3
#define VOCAB 50000
#define EMBD  128
#define SLEN  200
#define TOK   32
#define BATCH 64
#define QLEN  32
#define NSENT (BATCH*SLEN)        /* 12800 */
#define TBL   ((size_t)VOCAB*EMBD)
#define NTILE 3125                /* 16-wide vocab tiles for logits (3125*16 = 50000 exact) */
#define GMAIN 25600               /* gather main blocks: 3200 sent-groups x 8 chunks */
#define NWAVE 1024                /* waves in coop logits grid (256 blocks x 4) */

typedef short short8 __attribute__((ext_vector_type(8)));
typedef float f32x4  __attribute__((ext_vector_type(4)));
typedef unsigned u32x4 __attribute__((ext_vector_type(4)));

__device__ inline float bits2f(unsigned u){ union{unsigned u; float f;}c; c.u=u; return c.f; }
__device__ inline unsigned f2bits(float f){ union{float f; unsigned u;}c; c.f=f; return c.u; }
__device__ inline unsigned pack_bf16(float lo, float hi){
    unsigned ul = f2bits(lo), uh = f2bits(hi);
    unsigned rl = (ul + 0x7fffu + ((ul>>16)&1u)) >> 16;
    unsigned rh = (uh + 0x7fffu + ((uh>>16)&1u)) >> 16;
    return rl | (rh<<16);
}
__device__ inline unsigned short bf16of(float f){
    unsigned u = f2bits(f);
    return (unsigned short)((u + 0x7fffu + ((u>>16)&1u)) >> 16);
}

__device__ inline float waveSum(float v) {
    #pragma unroll
    for (int o = 32; o > 0; o >>= 1) v += __shfl_down(v, o, 64);
    return v;
}
__device__ inline float waveMax(float v) {
    #pragma unroll
    for (int o = 32; o > 0; o >>= 1) v = fmaxf(v, __shfl_down(v, o, 64));
    return v;
}

// ---------------------------------------------------------------------------
// Kernel 0: convert A fp32 -> interleaved bf16  Ab2[v][c(8)][k(4)][16].
// Output-centric: one thread per output uint4; writes 1 KB contiguous per
// wave, reads form 4 x 512 B contiguous runs (R7: fixed the write scatter).
// ---------------------------------------------------------------------------
__global__ __launch_bounds__(256) void conv_kernel(
    const float* __restrict__ A, u32x4* __restrict__ Ab2)
{
    int o = blockIdx.x*256 + threadIdx.x;      // uint4 index, 3.2M total
    int v = o >> 6;
    int c = (o >> 3) & 7;
    int k = (o >> 1) & 3;
    int h = o & 1;
    const f32x4* src = (const f32x4*)(A + (size_t)k*TBL + (size_t)v*EMBD + c*16 + h*8);
    f32x4 a = src[0], b = src[1];
    u32x4 r;
    r.x = pack_bf16(a.x,a.y); r.y = pack_bf16(a.z,a.w);
    r.z = pack_bf16(b.x,b.y); r.w = pack_bf16(b.z,b.w);
    Ab2[o] = r;
}

// ---------------------------------------------------------------------------
// Kernel A: gather-sum from interleaved bf16 tables (fp32 accumulate, BF16 G).
// Wave = one sentence x one 16-elem chunk, all 4 tables at once.
// Tail: 16 blocks, wave per batch b: u0[b] (fp32) from table 1.
// ---------------------------------------------------------------------------
__global__ __launch_bounds__(256) void gather_kernel(
    const unsigned* __restrict__ Ab2, const int* __restrict__ x,
    const int* __restrict__ q, unsigned short* __restrict__ Gb,
    float* __restrict__ uF)
{
    int B = blockIdx.x;
    int wid = threadIdx.x >> 6, lane = threadIdx.x & 63;
    if (B < GMAIN) {
        int c  = B & 7;
        int bs = (B >> 3)*4 + wid;
        int tok8 = lane >> 3, sub8 = lane & 7;
        int k = sub8 >> 1, half = sub8 & 1;
        const int* idxp = x + (size_t)bs * TOK;
        float a0=0.f,a1=0.f,a2=0.f,a3=0.f,a4=0.f,a5=0.f,a6=0.f,a7=0.f;
        #pragma unroll
        for (int r = 0; r < 4; r++) {
            int idx = idxp[r*8 + tok8];
            u32x4 v = *(const u32x4*)(Ab2 + (size_t)idx*256 + c*32 + k*8 + half*4);
            a0 += bits2f(v.x<<16); a1 += bits2f(v.x&0xffff0000u);
            a2 += bits2f(v.y<<16); a3 += bits2f(v.y&0xffff0000u);
            a4 += bits2f(v.z<<16); a5 += bits2f(v.z&0xffff0000u);
            a6 += bits2f(v.w<<16); a7 += bits2f(v.w&0xffff0000u);
        }
        #pragma unroll
        for (int o = 8; o <= 32; o <<= 1) {
            a0 += __shfl_xor(a0,o,64); a1 += __shfl_xor(a1,o,64);
            a2 += __shfl_xor(a2,o,64); a3 += __shfl_xor(a3,o,64);
            a4 += __shfl_xor(a4,o,64); a5 += __shfl_xor(a5,o,64);
            a6 += __shfl_xor(a6,o,64); a7 += __shfl_xor(a7,o,64);
        }
        if (tok8 == 0) {
            u32x4 w;
            w.x = pack_bf16(a0,a1); w.y = pack_bf16(a2,a3);
            w.z = pack_bf16(a4,a5); w.w = pack_bf16(a6,a7);
            *(u32x4*)(Gb + ((size_t)k*NSENT + bs)*EMBD + c*16 + half*8) = w;
        }
    } else {
        int b = (B - GMAIN)*4 + wid;
        int tok8 = lane >> 3, c = lane & 7;
        const int* idxp = q + (size_t)b * QLEN;
        float ac[16];
        #pragma unroll
        for (int i = 0; i < 16; i++) ac[i] = 0.f;
        #pragma unroll
        for (int r = 0; r < 4; r++) {
            int idx = idxp[r*8 + tok8];
            const unsigned* base = Ab2 + (size_t)idx*256 + c*32 + 8;  // k=1
            u32x4 v1 = *(const u32x4*)base;
            u32x4 v2 = *(const u32x4*)(base + 4);
            ac[0] += bits2f(v1.x<<16); ac[1] += bits2f(v1.x&0xffff0000u);
            ac[2] += bits2f(v1.y<<16); ac[3] += bits2f(v1.y&0xffff0000u);
            ac[4] += bits2f(v1.z<<16); ac[5] += bits2f(v1.z&0xffff0000u);
            ac[6] += bits2f(v1.w<<16); ac[7] += bits2f(v1.w&0xffff0000u);
            ac[8] += bits2f(v2.x<<16); ac[9] += bits2f(v2.x&0xffff0000u);
            ac[10]+= bits2f(v2.y<<16); ac[11]+= bits2f(v2.y&0xffff0000u);
            ac[12]+= bits2f(v2.z<<16); ac[13]+= bits2f(v2.z&0xffff0000u);
            ac[14]+= bits2f(v2.w<<16); ac[15]+= bits2f(v2.w&0xffff0000u);
        }
        #pragma unroll
        for (int o = 8; o <= 32; o <<= 1)
            #pragma unroll
            for (int i = 0; i < 16; i++) ac[i] += __shfl_xor(ac[i],o,64);
        if (tok8 < 4) {
            f32x4 rr;
            if      (tok8 == 0) { rr.x=ac[0];  rr.y=ac[1];  rr.z=ac[2];  rr.w=ac[3];  }
            else if (tok8 == 1) { rr.x=ac[4];  rr.y=ac[5];  rr.z=ac[6];  rr.w=ac[7];  }
            else if (tok8 == 2) { rr.x=ac[8];  rr.y=ac[9];  rr.z=ac[10]; rr.w=ac[11]; }
            else                { rr.x=ac[12]; rr.y=ac[13]; rr.z=ac[14]; rr.w=ac[15]; }
            *(f32x4*)(uF + (size_t)b*EMBD + c*16 + tok8*4) = rr;
        }
    }
}

// ---------------------------------------------------------------------------
// Kernel B: 3 hops, one block (1024 thr) per batch row, BF16 G.
// Per hop: combine's global loads (address-independent of softmax) are
// PREFETCHED first, hiding their latency behind the score/softmax phases.
// Combine also caches the converted G[k+1] slice in LDS (stride 132) for the
// next hop's score phase.
// ---------------------------------------------------------------------------
__global__ __launch_bounds__(1024) void hops_kernel(
    const unsigned short* __restrict__ Gb, const float* __restrict__ uF,
    const float* __restrict__ TA, const float* __restrict__ TC,
    unsigned short* __restrict__ ub)
{
    int b = blockIdx.x;
    int t = threadIdx.x;
    int lane = t & 63, wid = t >> 6;
    __shared__ __align__(16) float Gs[SLEN*132];
    __shared__ __align__(16) float uL[EMBD];
    __shared__ float p[256];
    __shared__ float red[16], red2[16];
    __shared__ float pc[7*EMBD];

    if (t < EMBD) uL[t] = uF[(size_t)b * EMBD + t];
    __syncthreads();

    int e = t & 127, ch = t >> 7;
    for (int k = 0; k < 3; k++) {
        // ---- prefetch combine loads (independent of everything below) ----
        const unsigned short* Gc = Gb + ((size_t)(k+1)*NSENT + (size_t)b*SLEN)*EMBD;
        unsigned short pre[25];
        #pragma unroll
        for (int j = 0; j < 25; j++) pre[j] = Gc[(size_t)(ch*25+j)*EMBD + e];
        // ---- sum(u) ----
        float v = (t < EMBD) ? uL[t] : 0.f;
        v = waveSum(v);
        if (lane == 0) red[wid] = v;
        __syncthreads();
        float sumU = 0.f;
        #pragma unroll
        for (int i = 0; i < 16; i++) sumU += red[i];
        // ---- scores: 4 threads per sentence ----
        int s = t >> 2, qd = t & 3;
        if (s < SLEN) {
            const float4* u4 = (const float4*)uL;
            float dot = 0.f;
            if (k == 0) {
                const u32x4* gb = (const u32x4*)(Gb + ((size_t)b*SLEN + s)*EMBD);
                #pragma unroll
                for (int i = 0; i < 4; i++) {
                    u32x4 gv = gb[qd*4 + i];
                    float4 u0 = u4[qd*8 + i*2];
                    float4 u1 = u4[qd*8 + i*2 + 1];
                    dot += bits2f(gv.x<<16)*u0.x + bits2f(gv.x&0xffff0000u)*u0.y
                         + bits2f(gv.y<<16)*u0.z + bits2f(gv.y&0xffff0000u)*u0.w
                         + bits2f(gv.z<<16)*u1.x + bits2f(gv.z&0xffff0000u)*u1.y
                         + bits2f(gv.w<<16)*u1.z + bits2f(gv.w&0xffff0000u)*u1.w;
                }
            } else {
                const float4* g4 = (const float4*)(Gs + s*132);
                #pragma unroll
                for (int i = 0; i < 8; i++) {
                    float4 gg = g4[qd*8+i], uu = u4[qd*8+i];
                    dot += gg.x*uu.x + gg.y*uu.y + gg.z*uu.z + gg.w*uu.w;
                }
            }
            dot += __shfl_xor(dot, 1, 64);
            dot += __shfl_xor(dot, 2, 64);
            if (qd == 0) p[s] = dot + TA[s]*sumU;
        }
        __syncthreads();
        float mv = (t < SLEN) ? p[t] : -3.4e38f;
        mv = waveMax(mv);
        if (lane == 0) red[wid] = mv;
        __syncthreads();
        float M = -3.4e38f;
        #pragma unroll
        for (int i = 0; i < 16; i++) M = fmaxf(M, red[i]);
        __syncthreads();
        float ev = 0.f, tc = 0.f;
        if (t < SLEN) { ev = __expf(p[t] - M); p[t] = ev; tc = ev * TC[t]; }
        float sv = waveSum(ev);
        float tv = waveSum(tc);
        if (lane == 0) { red[wid] = sv; red2[wid] = tv; }
        __syncthreads();
        float sumP = 0.f, pTC = 0.f;
        #pragma unroll
        for (int i = 0; i < 16; i++) { sumP += red[i]; pTC += red2[i]; }
        // ---- combine (uses prefetched values) + LDS-cache G[k+1][b] ----
        float acc = 0.f;
        #pragma unroll
        for (int j = 0; j < 25; j++) {
            float g = bits2f((unsigned)pre[j] << 16);
            Gs[(ch*25+j)*132 + e] = g;
            acc += p[ch*25+j] * g;
        }
        if (ch > 0) pc[(ch-1)*EMBD + e] = acc;
        __syncthreads();
        if (ch == 0) {
            #pragma unroll
            for (int c = 0; c < 7; c++) acc += pc[c*EMBD + e];
            uL[e] += (acc + pTC) / sumP;
        }
        __syncthreads();
    }
    if (t < EMBD) ub[(size_t)b * EMBD + t] = bf16of(uL[t]);
}

// ---------------------------------------------------------------------------
// Kernel C (cooperative): logits + log-softmax in ONE kernel.
// 256 blocks x 256 thr = 1024 waves; wave handles tiles w, w+1024, w+2048,
// w+3072 (<3125). Logits stay in registers across two grid.sync()s:
//   phase 1: MFMA logits + per-(row,wave) online (max,sumexp) partials
//   phase 2: 64 blocks reduce 1024 partials/row -> lse[64]
//   phase 3: out = acc - lse[row]  (single write of the output)
// ---------------------------------------------------------------------------
__global__ __launch_bounds__(256) void logits_coop(
    const unsigned* __restrict__ Ab2, const unsigned short* __restrict__ ub,
    float* __restrict__ out, float2* __restrict__ part, float* __restrict__ lse)
{
    cg::grid_group grid = cg::this_grid();
    __shared__ float sm[4], sl[4];
    int waveId = blockIdx.x*4 + (threadIdx.x >> 6);
    int lane = threadIdx.x & 63;
    int col = lane & 15, quad = lane >> 4;

    short8 af[4][4];
    #pragma unroll
    for (int bt = 0; bt < 4; bt++)
        #pragma unroll
        for (int kc = 0; kc < 4; kc++)
            af[bt][kc] = *(const short8*)(ub + (bt*16 + col)*EMBD + kc*32 + quad*8);

    f32x4 acc[4][4];
    float Mr[16], Lr[16];
    #pragma unroll
    for (int i = 0; i < 16; i++) { Mr[i] = -3.4e38f; Lr[i] = 0.f; }

    #pragma unroll
    for (int sl2 = 0; sl2 < 4; sl2++) {
        int w = waveId + sl2*NWAVE;
        if (w < NTILE) {
            int v0 = w*16;
            #pragma unroll
            for (int bt = 0; bt < 4; bt++) acc[sl2][bt] = (f32x4){0.f,0.f,0.f,0.f};
            #pragma unroll
            for (int kc = 0; kc < 4; kc++) {
                int c = kc*2 + (quad>>1);
                u32x4 braw = *(const u32x4*)(Ab2 + (size_t)(v0+col)*256 + c*32 + 24 + (quad&1)*4);
                short8 bf = *(short8*)&braw;
                #pragma unroll
                for (int bt = 0; bt < 4; bt++)
                    acc[sl2][bt] = __builtin_amdgcn_mfma_f32_16x16x32_bf16(af[bt][kc], bf, acc[sl2][bt], 0, 0, 0);
            }
            #pragma unroll
            for (int bt = 0; bt < 4; bt++)
                #pragma unroll
                for (int r = 0; r < 4; r++) {
                    float m = acc[sl2][bt][r];
                    #pragma unroll
                    for (int o = 1; o < 16; o <<= 1) m = fmaxf(m, __shfl_xor(m, o, 64));
                    float se = __expf(acc[sl2][bt][r] - m);
                    #pragma unroll
                    for (int o = 1; o < 16; o <<= 1) se += __shfl_xor(se, o, 64);
                    int i = bt*4 + r;
                    float nm = fmaxf(Mr[i], m);
                    Lr[i] = Lr[i]*__expf(Mr[i]-nm) + se*__expf(m-nm);
                    Mr[i] = nm;
                }
        }
    }
    if (col == 0) {
        #pragma unroll
        for (int bt = 0; bt < 4; bt++)
            #pragma unroll
            for (int r = 0; r < 4; r++) {
                int row = bt*16 + quad*4 + r;
                float2 pr; pr.x = Mr[bt*4+r]; pr.y = Lr[bt*4+r];
                part[(size_t)row*NWAVE + waveId] = pr;
            }
    }
    __threadfence();
    grid.sync();

    if (blockIdx.x < BATCH) {
        int row = blockIdx.x;
        float M = -3.4e38f, L = 0.f;
        for (int i = threadIdx.x; i < NWAVE; i += 256) {
            float2 pr = part[(size_t)row*NWAVE + i];
            float nm = fmaxf(M, pr.x);
            L = L*__expf(M-nm) + pr.y*__expf(pr.x-nm);
            M = nm;
        }
        #pragma unroll
        for (int o = 1; o < 64; o <<= 1) {
            float Mo = __shfl_xor(M,o,64), Lo = __shfl_xor(L,o,64);
            float nm = fmaxf(M,Mo);
            L = L*__expf(M-nm) + Lo*__expf(Mo-nm);
            M = nm;
        }
        int wid = threadIdx.x >> 6;
        if ((threadIdx.x & 63) == 0) { sm[wid] = M; sl[wid] = L; }
        __syncthreads();
        if (threadIdx.x == 0) {
            float Mf = -3.4e38f, Lf = 0.f;
            #pragma unroll
            for (int i2 = 0; i2 < 4; i2++) {
                float nm = fmaxf(Mf, sm[i2]);
                Lf = Lf*__expf(Mf-nm) + sl[i2]*__expf(sm[i2]-nm);
                Mf = nm;
            }
            lse[row] = Mf + __logf(Lf);
        }
    }
    __threadfence();
    grid.sync();

    #pragma unroll
    for (int sl2 = 0; sl2 < 4; sl2++) {
        int w = waveId + sl2*NWAVE;
        if (w < NTILE) {
            int v0 = w*16;
            #pragma unroll
            for (int bt = 0; bt < 4; bt++)
                #pragma unroll
                for (int r = 0; r < 4; r++) {
                    int row = bt*16 + quad*4 + r;
                    out[(size_t)row*VOCAB + v0 + col] = acc[sl2][bt][r] - lse[row];
                }
        }
    }
}

// ---------------------------------------------------------------------------
extern "C" void kernel_launch(void* const* d_in, const int* in_sizes, int n_in,
                              void* d_out, int out_size, void* d_ws, size_t ws_size,
                              hipStream_t stream)
{
    const float* A  = (const float*)d_in[0];   // [4, 50000, 128]
    const float* TA = (const float*)d_in[1];   // [200]
    const float* TC = (const float*)d_in[2];   // [200]
    const int*   x  = (const int*)d_in[3];     // [64, 200, 32]
    const int*   q  = (const int*)d_in[4];     // [64, 32]
    float* out = (float*)d_out;                // [64, 50000]

    // ws: Ab2 bf16 interleaved (51.2MB) | Gb bf16 (13.1MB) | uF | ub | part | lse
    unsigned* Ab2 = (unsigned*)d_ws;
    unsigned short* Gb = (unsigned short*)((char*)d_ws + (size_t)4*TBL*2);
    float* uF = (float*)(Gb + (size_t)4*NSENT*EMBD);
    unsigned short* ubp = (unsigned short*)(uF + (size_t)BATCH*EMBD);
    float2* part = (float2*)(ubp + (size_t)BATCH*EMBD);
    float* lseP = (float*)(part + (size_t)BATCH*NWAVE);

    conv_kernel  <<<VOCAB*64/256, 256, 0, stream>>>(A, (u32x4*)Ab2);
    gather_kernel<<<GMAIN + 16, 256, 0, stream>>>(Ab2, x, q, Gb, uF);
    hops_kernel  <<<BATCH, 1024, 0, stream>>>(Gb, uF, TA, TC, ubp);

    void* args[5];
    const unsigned* pAb2 = Ab2;
    const unsigned short* pub = ubp;
    args[0] = (void*)&pAb2;
    args[1] = (void*)&pub;
    args[2] = (void*)&out;
    args[3] = (void*)&part;
    args[4] = (void*)&lseP;
    hipLaunchCooperativeKernel((const void*)logits_coop, dim3(256), dim3(256),
                               args, 0, stream);
}

// Round 9
// 274.983 us; speedup vs baseline: 1.3938x; 1.3938x over previous
//
#include <hip/hip_runtime.h>
#include <math.h>

// MemNN forward: B=64, S=200, T=32, E=128, V=50000, HOPS=3
#define VOCAB 50000
#define EMBD  128
#define SLEN  200
#define TOK   32
#define BATCH 64
#define QLEN  32
#define NSENT (BATCH*SLEN)        /* 12800 */
#define TBL   ((size_t)VOCAB*EMBD)
#define NTILE 3125                /* 16-wide vocab tiles (3125*16 = 50000 exact) */
#define GMAIN 25600               /* gather main blocks: 3200 sent-groups x 8 chunks */

typedef short short8 __attribute__((ext_vector_type(8)));
typedef float f32x4  __attribute__((ext_vector_type(4)));
typedef unsigned u32x4 __attribute__((ext_vector_type(4)));

__device__ inline float bits2f(unsigned u){ union{unsigned u; float f;}c; c.u=u; return c.f; }
__device__ inline unsigned f2bits(float f){ union{float f; unsigned u;}c; c.f=f; return c.u; }
__device__ inline unsigned pack_bf16(float lo, float hi){
    unsigned ul = f2bits(lo), uh = f2bits(hi);
    unsigned rl = (ul + 0x7fffu + ((ul>>16)&1u)) >> 16;
    unsigned rh = (uh + 0x7fffu + ((uh>>16)&1u)) >> 16;
    return rl | (rh<<16);
}
__device__ inline unsigned short bf16of(float f){
    unsigned u = f2bits(f);
    return (unsigned short)((u + 0x7fffu + ((u>>16)&1u)) >> 16);
}

__device__ inline float waveSum(float v) {
    #pragma unroll
    for (int o = 32; o > 0; o >>= 1) v += __shfl_down(v, o, 64);
    return v;
}
__device__ inline float waveMax(float v) {
    #pragma unroll
    for (int o = 32; o > 0; o >>= 1) v = fmaxf(v, __shfl_down(v, o, 64));
    return v;
}

// ---------------------------------------------------------------------------
// Kernel 0: convert A fp32 -> interleaved bf16  Ab2[v][c(8)][k(4)][16].
// Output-centric: one thread per output uint4; writes 1 KB contiguous per
// wave, reads form 4 x 512 B contiguous runs (R7: fixed the write scatter).
// ---------------------------------------------------------------------------
__global__ __launch_bounds__(256) void conv_kernel(
    const float* __restrict__ A, u32x4* __restrict__ Ab2)
{
    int o = blockIdx.x*256 + threadIdx.x;      // uint4 index, 3.2M total
    int v = o >> 6;
    int c = (o >> 3) & 7;
    int k = (o >> 1) & 3;
    int h = o & 1;
    const f32x4* src = (const f32x4*)(A + (size_t)k*TBL + (size_t)v*EMBD + c*16 + h*8);
    f32x4 a = src[0], b = src[1];
    u32x4 r;
    r.x = pack_bf16(a.x,a.y); r.y = pack_bf16(a.z,a.w);
    r.z = pack_bf16(b.x,b.y); r.w = pack_bf16(b.z,b.w);
    Ab2[o] = r;
}

// ---------------------------------------------------------------------------
// Kernel A: gather-sum from interleaved bf16 tables (fp32 accumulate, BF16 G
// output halves write traffic). Wave = one sentence x one 16-elem chunk, all
// 4 tables at once. Tail: 16 blocks, wave per batch b: u0[b] fp32.
// ---------------------------------------------------------------------------
__global__ __launch_bounds__(256) void gather_kernel(
    const unsigned* __restrict__ Ab2, const int* __restrict__ x,
    const int* __restrict__ q, unsigned short* __restrict__ Gb,
    float* __restrict__ uF)
{
    int B = blockIdx.x;
    int wid = threadIdx.x >> 6, lane = threadIdx.x & 63;
    if (B < GMAIN) {
        int c  = B & 7;
        int bs = (B >> 3)*4 + wid;
        int tok8 = lane >> 3, sub8 = lane & 7;
        int k = sub8 >> 1, half = sub8 & 1;
        const int* idxp = x + (size_t)bs * TOK;
        float a0=0.f,a1=0.f,a2=0.f,a3=0.f,a4=0.f,a5=0.f,a6=0.f,a7=0.f;
        #pragma unroll
        for (int r = 0; r < 4; r++) {
            int idx = idxp[r*8 + tok8];
            u32x4 v = *(const u32x4*)(Ab2 + (size_t)idx*256 + c*32 + k*8 + half*4);
            a0 += bits2f(v.x<<16); a1 += bits2f(v.x&0xffff0000u);
            a2 += bits2f(v.y<<16); a3 += bits2f(v.y&0xffff0000u);
            a4 += bits2f(v.z<<16); a5 += bits2f(v.z&0xffff0000u);
            a6 += bits2f(v.w<<16); a7 += bits2f(v.w&0xffff0000u);
        }
        #pragma unroll
        for (int o = 8; o <= 32; o <<= 1) {
            a0 += __shfl_xor(a0,o,64); a1 += __shfl_xor(a1,o,64);
            a2 += __shfl_xor(a2,o,64); a3 += __shfl_xor(a3,o,64);
            a4 += __shfl_xor(a4,o,64); a5 += __shfl_xor(a5,o,64);
            a6 += __shfl_xor(a6,o,64); a7 += __shfl_xor(a7,o,64);
        }
        if (tok8 == 0) {
            u32x4 w;
            w.x = pack_bf16(a0,a1); w.y = pack_bf16(a2,a3);
            w.z = pack_bf16(a4,a5); w.w = pack_bf16(a6,a7);
            *(u32x4*)(Gb + ((size_t)k*NSENT + bs)*EMBD + c*16 + half*8) = w;
        }
    } else {
        int b = (B - GMAIN)*4 + wid;
        int tok8 = lane >> 3, c = lane & 7;
        const int* idxp = q + (size_t)b * QLEN;
        float ac[16];
        #pragma unroll
        for (int i = 0; i < 16; i++) ac[i] = 0.f;
        #pragma unroll
        for (int r = 0; r < 4; r++) {
            int idx = idxp[r*8 + tok8];
            const unsigned* base = Ab2 + (size_t)idx*256 + c*32 + 8;  // k=1
            u32x4 v1 = *(const u32x4*)base;
            u32x4 v2 = *(const u32x4*)(base + 4);
            ac[0] += bits2f(v1.x<<16); ac[1] += bits2f(v1.x&0xffff0000u);
            ac[2] += bits2f(v1.y<<16); ac[3] += bits2f(v1.y&0xffff0000u);
            ac[4] += bits2f(v1.z<<16); ac[5] += bits2f(v1.z&0xffff0000u);
            ac[6] += bits2f(v1.w<<16); ac[7] += bits2f(v1.w&0xffff0000u);
            ac[8] += bits2f(v2.x<<16); ac[9] += bits2f(v2.x&0xffff0000u);
            ac[10]+= bits2f(v2.y<<16); ac[11]+= bits2f(v2.y&0xffff0000u);
            ac[12]+= bits2f(v2.z<<16); ac[13]+= bits2f(v2.z&0xffff0000u);
            ac[14]+= bits2f(v2.w<<16); ac[15]+= bits2f(v2.w&0xffff0000u);
        }
        #pragma unroll
        for (int o = 8; o <= 32; o <<= 1)
            #pragma unroll
            for (int i = 0; i < 16; i++) ac[i] += __shfl_xor(ac[i],o,64);
        if (tok8 < 4) {
            f32x4 rr;
            if      (tok8 == 0) { rr.x=ac[0];  rr.y=ac[1];  rr.z=ac[2];  rr.w=ac[3];  }
            else if (tok8 == 1) { rr.x=ac[4];  rr.y=ac[5];  rr.z=ac[6];  rr.w=ac[7];  }
            else if (tok8 == 2) { rr.x=ac[8];  rr.y=ac[9];  rr.z=ac[10]; rr.w=ac[11]; }
            else                { rr.x=ac[12]; rr.y=ac[13]; rr.z=ac[14]; rr.w=ac[15]; }
            *(f32x4*)(uF + (size_t)b*EMBD + c*16 + tok8*4) = rr;
        }
    }
}

// ---------------------------------------------------------------------------
// Kernel B: 3 hops, one block (1024 thr) per batch row, BF16 G.
// Combine's global loads are PREFETCHED at hop start (independent of the
// softmax), hiding their latency behind score/softmax. Combine caches the
// converted G[k+1] slice in LDS (stride 132) for the next hop's score.
// ---------------------------------------------------------------------------
__global__ __launch_bounds__(1024) void hops_kernel(
    const unsigned short* __restrict__ Gb, const float* __restrict__ uF,
    const float* __restrict__ TA, const float* __restrict__ TC,
    unsigned short* __restrict__ ub)
{
    int b = blockIdx.x;
    int t = threadIdx.x;
    int lane = t & 63, wid = t >> 6;
    __shared__ __align__(16) float Gs[SLEN*132];
    __shared__ __align__(16) float uL[EMBD];
    __shared__ float p[256];
    __shared__ float red[16], red2[16];
    __shared__ float pc[7*EMBD];

    if (t < EMBD) uL[t] = uF[(size_t)b * EMBD + t];
    __syncthreads();

    int e = t & 127, ch = t >> 7;
    for (int k = 0; k < 3; k++) {
        // ---- prefetch combine loads ----
        const unsigned short* Gc = Gb + ((size_t)(k+1)*NSENT + (size_t)b*SLEN)*EMBD;
        unsigned short pre[25];
        #pragma unroll
        for (int j = 0; j < 25; j++) pre[j] = Gc[(size_t)(ch*25+j)*EMBD + e];
        // ---- sum(u) ----
        float v = (t < EMBD) ? uL[t] : 0.f;
        v = waveSum(v);
        if (lane == 0) red[wid] = v;
        __syncthreads();
        float sumU = 0.f;
        #pragma unroll
        for (int i = 0; i < 16; i++) sumU += red[i];
        // ---- scores: 4 threads per sentence ----
        int s = t >> 2, qd = t & 3;
        if (s < SLEN) {
            const float4* u4 = (const float4*)uL;
            float dot = 0.f;
            if (k == 0) {
                const u32x4* gb = (const u32x4*)(Gb + ((size_t)b*SLEN + s)*EMBD);
                #pragma unroll
                for (int i = 0; i < 4; i++) {
                    u32x4 gv = gb[qd*4 + i];
                    float4 u0 = u4[qd*8 + i*2];
                    float4 u1 = u4[qd*8 + i*2 + 1];
                    dot += bits2f(gv.x<<16)*u0.x + bits2f(gv.x&0xffff0000u)*u0.y
                         + bits2f(gv.y<<16)*u0.z + bits2f(gv.y&0xffff0000u)*u0.w
                         + bits2f(gv.z<<16)*u1.x + bits2f(gv.z&0xffff0000u)*u1.y
                         + bits2f(gv.w<<16)*u1.z + bits2f(gv.w&0xffff0000u)*u1.w;
                }
            } else {
                const float4* g4 = (const float4*)(Gs + s*132);
                #pragma unroll
                for (int i = 0; i < 8; i++) {
                    float4 gg = g4[qd*8+i], uu = u4[qd*8+i];
                    dot += gg.x*uu.x + gg.y*uu.y + gg.z*uu.z + gg.w*uu.w;
                }
            }
            dot += __shfl_xor(dot, 1, 64);
            dot += __shfl_xor(dot, 2, 64);
            if (qd == 0) p[s] = dot + TA[s]*sumU;
        }
        __syncthreads();
        float mv = (t < SLEN) ? p[t] : -3.4e38f;
        mv = waveMax(mv);
        if (lane == 0) red[wid] = mv;
        __syncthreads();
        float M = -3.4e38f;
        #pragma unroll
        for (int i = 0; i < 16; i++) M = fmaxf(M, red[i]);
        __syncthreads();
        float ev = 0.f, tc = 0.f;
        if (t < SLEN) { ev = __expf(p[t] - M); p[t] = ev; tc = ev * TC[t]; }
        float sv = waveSum(ev);
        float tv = waveSum(tc);
        if (lane == 0) { red[wid] = sv; red2[wid] = tv; }
        __syncthreads();
        float sumP = 0.f, pTC = 0.f;
        #pragma unroll
        for (int i = 0; i < 16; i++) { sumP += red[i]; pTC += red2[i]; }
        // ---- combine (prefetched) + LDS-cache G[k+1][b] ----
        float acc = 0.f;
        #pragma unroll
        for (int j = 0; j < 25; j++) {
            float g = bits2f((unsigned)pre[j] << 16);
            Gs[(ch*25+j)*132 + e] = g;
            acc += p[ch*25+j] * g;
        }
        if (ch > 0) pc[(ch-1)*EMBD + e] = acc;
        __syncthreads();
        if (ch == 0) {
            #pragma unroll
            for (int c = 0; c < 7; c++) acc += pc[c*EMBD + e];
            uL[e] += (acc + pTC) / sumP;
        }
        __syncthreads();
    }
    if (t < EMBD) ub[(size_t)b * EMBD + t] = bf16of(uL[t]);
}

// ---------------------------------------------------------------------------
// Kernel C: MFMA logits from interleaved layout. Wave per 16-vocab tile.
// B-frag for (kc,quad): chunk c=kc*2+(quad>>1), k=3 slot, 16B contiguous.
// Fused per-(row,tile) max/sumexp partials -> part.
// ---------------------------------------------------------------------------
__global__ __launch_bounds__(256) void logits_mfma(
    const unsigned* __restrict__ Ab2, const unsigned short* __restrict__ ub,
    float* __restrict__ out, float* __restrict__ part)
{
    int w = blockIdx.x*4 + (threadIdx.x >> 6);
    if (w >= NTILE) return;
    int lane = threadIdx.x & 63;
    int col = lane & 15, quad = lane >> 4;
    int v0 = w * 16;

    short8 af[4][4];
    #pragma unroll
    for (int bt = 0; bt < 4; bt++)
        #pragma unroll
        for (int kc = 0; kc < 4; kc++)
            af[bt][kc] = *(const short8*)(ub + (bt*16 + col)*EMBD + kc*32 + quad*8);

    f32x4 acc[4];
    #pragma unroll
    for (int bt = 0; bt < 4; bt++) acc[bt] = (f32x4){0.f, 0.f, 0.f, 0.f};

    #pragma unroll
    for (int kc = 0; kc < 4; kc++) {
        int c = kc*2 + (quad>>1);
        const u32x4* bp = (const u32x4*)(Ab2 + (size_t)(v0+col)*256 + c*32 + 24 + (quad&1)*4);
        u32x4 braw = *bp;
        short8 bf = *(short8*)&braw;
        #pragma unroll
        for (int bt = 0; bt < 4; bt++)
            acc[bt] = __builtin_amdgcn_mfma_f32_16x16x32_bf16(af[bt][kc], bf, acc[bt], 0, 0, 0);
    }

    #pragma unroll
    for (int bt = 0; bt < 4; bt++) {
        #pragma unroll
        for (int r = 0; r < 4; r++) {
            int bI = bt*16 + quad*4 + r;
            out[(size_t)bI * VOCAB + v0 + col] = acc[bt][r];
        }
        #pragma unroll
        for (int r = 0; r < 4; r++) {
            float m = acc[bt][r];
            #pragma unroll
            for (int o = 1; o < 16; o <<= 1) m = fmaxf(m, __shfl_xor(m, o, 64));
            float se = __expf(acc[bt][r] - m);
            #pragma unroll
            for (int o = 1; o < 16; o <<= 1) se += __shfl_xor(se, o, 64);
            if (col == 0) {
                int bI = bt*16 + quad*4 + r;
                float2 pr; pr.x = m; pr.y = se;
                ((float2*)part)[(size_t)bI * NTILE + w] = pr;
            }
        }
    }
}

// ---------------------------------------------------------------------------
// Kernel D: fused lse + normalize (64 rows x 49 chunks).
// ---------------------------------------------------------------------------
__global__ __launch_bounds__(256) void norm_kernel(
    float* __restrict__ out, const float* __restrict__ part)
{
    int b = blockIdx.x / 49, c = blockIdx.x % 49;
    int t = threadIdx.x, lane = t & 63, wid = t >> 6;
    __shared__ float sm[4], sl[4];
    const float2* P = (const float2*)part + (size_t)b * NTILE;
    float M = -3.4e38f, L = 0.f;
    for (int i = t; i < NTILE; i += 256) {
        float2 pr = P[i];
        float m2 = fmaxf(M, pr.x);
        L = L * __expf(M - m2) + pr.y * __expf(pr.x - m2);
        M = m2;
    }
    #pragma unroll
    for (int o = 1; o < 64; o <<= 1) {
        float Mo = __shfl_xor(M, o, 64), Lo = __shfl_xor(L, o, 64);
        float m2 = fmaxf(M, Mo);
        L = L * __expf(M - m2) + Lo * __expf(Mo - m2);
        M = m2;
    }
    if (lane == 0) { sm[wid] = M; sl[wid] = L; }
    __syncthreads();
    float Mf = -3.4e38f, Lf = 0.f;
    #pragma unroll
    for (int i = 0; i < 4; i++) {
        float m2 = fmaxf(Mf, sm[i]);
        Lf = Lf * __expf(Mf - m2) + sl[i] * __expf(sm[i] - m2);
        Mf = m2;
    }
    float lse = Mf + __logf(Lf);
    int f4 = c * 256 + t;
    if (f4 < VOCAB/4) {
        float4* rowp = (float4*)(out + (size_t)b * VOCAB);
        float4 v = rowp[f4];
        v.x -= lse; v.y -= lse; v.z -= lse; v.w -= lse;
        rowp[f4] = v;
    }
}

// ---------------------------------------------------------------------------
extern "C" void kernel_launch(void* const* d_in, const int* in_sizes, int n_in,
                              void* d_out, int out_size, void* d_ws, size_t ws_size,
                              hipStream_t stream)
{
    const float* A  = (const float*)d_in[0];   // [4, 50000, 128]
    const float* TA = (const float*)d_in[1];   // [200]
    const float* TC = (const float*)d_in[2];   // [200]
    const int*   x  = (const int*)d_in[3];     // [64, 200, 32]
    const int*   q  = (const int*)d_in[4];     // [64, 32]
    float* out = (float*)d_out;                // [64, 50000]

    // ws: Ab2 bf16 interleaved (51.2MB) | Gb bf16 (13.1MB) | uF | ub | part
    unsigned* Ab2 = (unsigned*)d_ws;
    unsigned short* Gb = (unsigned short*)((char*)d_ws + (size_t)4*TBL*2);
    float* uF = (float*)(Gb + (size_t)4*NSENT*EMBD);
    unsigned short* ubp = (unsigned short*)(uF + (size_t)BATCH*EMBD);
    float* part = (float*)(ubp + (size_t)BATCH*EMBD);

    conv_kernel  <<<VOCAB*64/256, 256, 0, stream>>>(A, (u32x4*)Ab2);
    gather_kernel<<<GMAIN + 16, 256, 0, stream>>>(Ab2, x, q, Gb, uF);
    hops_kernel  <<<BATCH, 1024, 0, stream>>>(Gb, uF, TA, TC, ubp);
    logits_mfma  <<<(NTILE+3)/4, 256, 0, stream>>>(Ab2, ubp, out, part);
    norm_kernel  <<<BATCH*49, 256, 0, stream>>>(out, part);
}